// Round 1
// baseline (4976.840 us; speedup 1.0000x reference)
//
#include <hip/hip_runtime.h>

#define NN 4096
#define HD 64
#define KNB 15
#define NE 32768
#define NM (NE + NN*KNB)   // 94208 edges total (with duplicates)
#define W64 (NN/64)        // 64 u64 words per bitmap row

typedef unsigned long long u64;
typedef unsigned int u32;

// order-preserving float->uint map (for atomicMax on floats)
__device__ __forceinline__ u32 fmapu(float f) {
  int i = __float_as_int(f);
  return (u32)(i ^ ((i >> 31) | 0x80000000));
}
__device__ __forceinline__ float fumap(u32 u) {
  u32 i = (u & 0x80000000u) ? (u ^ 0x80000000u) : ~u;
  return __int_as_float((int)i);
}

__device__ __forceinline__ float dot64(const float* __restrict__ a,
                                       const float* __restrict__ b) {
  const float4* a4 = (const float4*)a;
  const float4* b4 = (const float4*)b;
  float s = 0.f;
#pragma unroll
  for (int t = 0; t < 16; ++t) {
    float4 x = a4[t], y = b4[t];
    s = fmaf(x.x, y.x, s); s = fmaf(x.y, y.y, s);
    s = fmaf(x.z, y.z, s); s = fmaf(x.w, y.w, s);
  }
  return s;
}

__device__ __forceinline__ void edge_decode(int m, const int* __restrict__ ei,
                                            const int* __restrict__ knn_idx,
                                            int& s, int& d) {
  if (m < NE) { s = ei[m]; d = ei[NE + m]; }
  else { int mm = m - NE; s = mm / KNB; d = knn_idx[mm]; }
}

__global__ void zero_kernel(u32* __restrict__ p, int n) {
  int i = blockIdx.x * 256 + threadIdx.x;
  int stride = gridDim.x * 256;
  for (; i < n; i += stride) p[i] = 0u;
}

// ---------- KNN: brute force, top-15 smallest d2 (lex tie-break on index) ----
__global__ __launch_bounds__(256) void knn_kernel(const float* __restrict__ pts,
                                                  int* __restrict__ knn_idx) {
  __shared__ float sx[NN], sy[NN], sz[NN], ssq[NN];  // 64KB
  int tid = threadIdx.x;
  for (int j = tid; j < NN; j += 256) {
    float x = pts[j*3+0], y = pts[j*3+1], z = pts[j*3+2];
    sx[j] = x; sy[j] = y; sz[j] = z;
    // match np: (x*x + y*y) + z*z, no fma contraction
    ssq[j] = __fadd_rn(__fadd_rn(__fmul_rn(x,x), __fmul_rn(y,y)), __fmul_rn(z,z));
  }
  __syncthreads();
  int i = blockIdx.x * 256 + tid;
  float px = sx[i], py = sy[i], pz = sz[i], sqi = ssq[i];
  float bd[KNB]; int bi[KNB];
#pragma unroll
  for (int s = 0; s < KNB; ++s) { bd[s] = INFINITY; bi[s] = NN; }
  for (int j = 0; j < NN; ++j) {
    if (j == i) continue;
    // match BLAS fma chain: acc = x*xj; fma(y,..); fma(z,..)
    float dot = fmaf(pz, sz[j], fmaf(py, sy[j], __fmul_rn(px, sx[j])));
    float d2 = __fadd_rn(__fsub_rn(sqi, __fmul_rn(2.0f, dot)), ssq[j]);
    float wd = bd[KNB-1]; int wi = bi[KNB-1];
    if (d2 < wd || (d2 == wd && j < wi)) {
      bd[KNB-1] = d2; bi[KNB-1] = j;
#pragma unroll
      for (int s = KNB-1; s > 0; --s) {
        bool sw = (bd[s] < bd[s-1]) || (bd[s] == bd[s-1] && bi[s] < bi[s-1]);
        if (sw) {
          float td = bd[s]; bd[s] = bd[s-1]; bd[s-1] = td;
          int ti = bi[s]; bi[s] = bi[s-1]; bi[s-1] = ti;
        }
      }
    }
  }
#pragma unroll
  for (int s = 0; s < KNB; ++s) knn_idx[i*KNB + s] = bi[s];
}

// ---------- mark unique edges in row- and col-bitmaps ----------
__global__ void bitmap_kernel(const int* __restrict__ ei, const int* __restrict__ knn_idx,
                              u64* __restrict__ bR, u64* __restrict__ bC) {
  int m = blockIdx.x * 256 + threadIdx.x;
  if (m >= NM) return;
  int s, d; edge_decode(m, ei, knn_idx, s, d);
  atomicOr(&bR[(size_t)s*W64 + (d >> 6)], 1ull << (d & 63));
  atomicOr(&bC[(size_t)d*W64 + (s >> 6)], 1ull << (s & 63));
}

// ---------- h = W_theta (p_d - p_s) + b; segment_max over src (all M edges) --
__global__ void theta_max_kernel(const float* __restrict__ pts, const int* __restrict__ ei,
                                 const int* __restrict__ knn_idx,
                                 const float* __restrict__ Wt, const float* __restrict__ bt,
                                 u32* __restrict__ maxu) {
  int g = blockIdx.x * 256 + threadIdx.x;
  if (g >= NM * HD) return;
  int m = g >> 6, dim = g & 63;
  int s, d; edge_decode(m, ei, knn_idx, s, d);
  float dx = __fsub_rn(pts[d*3+0], pts[s*3+0]);
  float dy = __fsub_rn(pts[d*3+1], pts[s*3+1]);
  float dz = __fsub_rn(pts[d*3+2], pts[s*3+2]);
  float t = fmaf(dz, Wt[dim*3+2], fmaf(dy, Wt[dim*3+1], __fmul_rn(dx, Wt[dim*3+0])));
  float hv = __fadd_rn(t, bt[dim]);
  atomicMax(&maxu[(size_t)s*HD + dim], fmapu(hv));
}

// ---------- dev = relu(W_phi maxf + b); q, k ----------
__global__ __launch_bounds__(256) void dev_qk_kernel(const u32* __restrict__ maxu,
    const float* __restrict__ Wp, const float* __restrict__ bp,
    const float* __restrict__ Wq, const float* __restrict__ bq,
    const float* __restrict__ Wk, const float* __restrict__ bk,
    float* __restrict__ qv, float* __restrict__ kv) {
  __shared__ float mf[4][HD];
  __shared__ float dv[4][HD];
  int lane = threadIdx.x & 63, sub = threadIdx.x >> 6;
  int node = blockIdx.x * 4 + sub;
  mf[sub][lane] = fumap(maxu[(size_t)node*HD + lane]);
  __syncthreads();
  float a = 0.f;
#pragma unroll
  for (int t = 0; t < HD; ++t) a = fmaf(Wp[lane*HD + t], mf[sub][t], a);
  float dvv = a + bp[lane];
  dv[sub][lane] = dvv > 0.f ? dvv : 0.f;
  __syncthreads();
  float aq = 0.f, ak = 0.f;
#pragma unroll
  for (int t = 0; t < HD; ++t) {
    float x = dv[sub][t];
    aq = fmaf(Wq[lane*HD + t], x, aq);
    ak = fmaf(Wk[lane*HD + t], x, ak);
  }
  qv[(size_t)node*HD + lane] = aq + bq[lane];
  kv[(size_t)node*HD + lane] = ak + bk[lane];
}

// ---------- denom[s] = sum over ALL M edges of exp(q[d].k[s]) ----------
__global__ void denom_kernel(const int* __restrict__ ei, const int* __restrict__ knn_idx,
                             const float* __restrict__ qv, const float* __restrict__ kv,
                             float* __restrict__ denom) {
  int m = blockIdx.x * 256 + threadIdx.x;
  if (m >= NM) return;
  int s, d; edge_decode(m, ei, knn_idx, s, d);
  float e = expf(dot64(qv + (size_t)d*HD, kv + (size_t)s*HD));
  atomicAdd(&denom[s], e);
}

// ---------- degrees from bitmaps ----------
__global__ void deg_kernel(const u64* __restrict__ bR, const u64* __restrict__ bC,
                           int* __restrict__ outdeg, int* __restrict__ indeg) {
  int i = blockIdx.x * 256 + threadIdx.x;
  if (i >= NN) return;
  int c = 0;
  for (int w = 0; w < W64; ++w) c += __popcll(bR[(size_t)i*W64 + w]);
  outdeg[i] = c;
  c = 0;
  for (int w = 0; w < W64; ++w) c += __popcll(bC[(size_t)i*W64 + w]);
  indeg[i] = c;
}

// ---------- exclusive scan of 4096 ints, single block ----------
__global__ __launch_bounds__(1024) void scan_kernel(const int* __restrict__ deg,
                                                    int* __restrict__ ptr) {
  __shared__ int part[1024];
  int t = threadIdx.x;
  int base = t * 4;
  int a0 = deg[base], a1 = deg[base+1], a2 = deg[base+2], a3 = deg[base+3];
  part[t] = a0 + a1 + a2 + a3;
  __syncthreads();
  for (int off = 1; off < 1024; off <<= 1) {
    int v = 0;
    if (t >= off) v = part[t - off];
    __syncthreads();
    if (t >= off) part[t] += v;
    __syncthreads();
  }
  int excl = (t > 0) ? part[t-1] : 0;
  ptr[base]   = excl;
  ptr[base+1] = excl + a0;
  ptr[base+2] = excl + a0 + a1;
  ptr[base+3] = excl + a0 + a1 + a2;
  if (t == 1023) ptr[NN] = part[1023];
}

// ---------- CSR fill (row i: cols k, val = attn[i,k]) ----------
__global__ void fill_csr_kernel(const u64* __restrict__ bR, const int* __restrict__ row_ptr,
                                const float* __restrict__ qv, const float* __restrict__ kv,
                                const float* __restrict__ denom,
                                int* __restrict__ csr_col, float* __restrict__ csr_val) {
  int i = blockIdx.x * 256 + threadIdx.x;
  if (i >= NN) return;
  int off = row_ptr[i];
  float dn = denom[i];
  const float* ki = kv + (size_t)i*HD;
  for (int w = 0; w < W64; ++w) {
    u64 b = bR[(size_t)i*W64 + w];
    while (b) {
      int t = __builtin_ctzll(b); b &= b - 1;
      int col = w*64 + t;
      float e = expf(dot64(qv + (size_t)col*HD, ki));
      csr_col[off] = col; csr_val[off] = e / dn; ++off;
    }
  }
}

// ---------- CSC fill (col l: rows j, val = attn[j,l]) ----------
__global__ void fill_csc_kernel(const u64* __restrict__ bC, const int* __restrict__ col_ptr,
                                const float* __restrict__ qv, const float* __restrict__ kv,
                                const float* __restrict__ denom,
                                int* __restrict__ csc_row, float* __restrict__ csc_val) {
  int l = blockIdx.x * 256 + threadIdx.x;
  if (l >= NN) return;
  int off = col_ptr[l];
  const float* ql = qv + (size_t)l*HD;
  for (int w = 0; w < W64; ++w) {
    u64 b = bC[(size_t)l*W64 + w];
    while (b) {
      int t = __builtin_ctzll(b); b &= b - 1;
      int j = w*64 + t;
      float e = expf(dot64(ql, kv + (size_t)j*HD));
      csc_row[off] = j; csc_val[off] = e / denom[j]; ++off;
    }
  }
}

// ---------- A_s row i = sum_l T[i,l] * attn[:,l], T = attn@A ----------
__global__ __launch_bounds__(256) void final_kernel(
    const int* __restrict__ row_ptr, const int* __restrict__ csr_col,
    const float* __restrict__ csr_val,
    const int* __restrict__ col_ptr, const int* __restrict__ csc_row,
    const float* __restrict__ csc_val,
    float* __restrict__ out) {
  __shared__ float Trow[NN];  // 16KB
  __shared__ float acc[NN];   // 16KB
  int tid = threadIdx.x;
  int i = blockIdx.x;
  for (int t = tid; t < NN; t += 256) { Trow[t] = 0.f; acc[t] = 0.f; }
  __syncthreads();
  int rb = row_ptr[i], re = row_ptr[i+1];
  int wave = tid >> 6, lane = tid & 63;
  // Phase A: Trow[l] += w_ik for l in out(k), k in out(i)
  for (int idx = rb + wave; idx < re; idx += 4) {
    int k = csr_col[idx]; float wv = csr_val[idx];
    int kb = row_ptr[k], ke = row_ptr[k+1];
    for (int t = kb + lane; t < ke; t += 64) {
      atomicAdd(&Trow[csr_col[t]], wv);
    }
  }
  __syncthreads();
  // Phase B: acc[j] += Trow[l] * attn[j,l]
  for (int l = tid; l < NN; l += 256) {
    float tv = Trow[l];
    if (tv != 0.f) {
      int cb = col_ptr[l], ce = col_ptr[l+1];
      for (int t = cb; t < ce; ++t) {
        atomicAdd(&acc[csc_row[t]], tv * csc_val[t]);
      }
    }
  }
  __syncthreads();
  float4* o = (float4*)(out + (size_t)i * NN);
  const float4* a4 = (const float4*)acc;
  for (int t = tid; t < NN/4; t += 256) o[t] = a4[t];
}

extern "C" void kernel_launch(void* const* d_in, const int* in_sizes, int n_in,
                              void* d_out, int out_size, void* d_ws, size_t ws_size,
                              hipStream_t stream) {
  (void)in_sizes; (void)n_in; (void)out_size;
  const float* pts = (const float*)d_in[0];
  // d_in[1] = features: unused by the reference
  const int* ei = (const int*)d_in[2];
  const float* Wt = (const float*)d_in[3];
  const float* bt = (const float*)d_in[4];
  const float* Wp = (const float*)d_in[5];
  const float* bp = (const float*)d_in[6];
  const float* Wq = (const float*)d_in[7];
  const float* bq = (const float*)d_in[8];
  const float* Wk = (const float*)d_in[9];
  const float* bk = (const float*)d_in[10];
  float* out = (float*)d_out;

  char* w = (char*)d_ws;
  u64* bR = (u64*)w;        w += (size_t)NN*W64*8;   // 2MB
  u64* bC = (u64*)w;        w += (size_t)NN*W64*8;   // 2MB
  u32* maxu = (u32*)w;      w += (size_t)NN*HD*4;    // 1MB
  float* denom = (float*)w; w += (size_t)NN*4;       // 16KB
  float* qv = (float*)w;    w += (size_t)NN*HD*4;    // 1MB
  float* kv = (float*)w;    w += (size_t)NN*HD*4;    // 1MB
  int* knn_idx = (int*)w;   w += (size_t)NN*KNB*4;
  int* outdeg = (int*)w;    w += (size_t)NN*4;
  int* indeg = (int*)w;     w += (size_t)NN*4;
  int* row_ptr = (int*)w;   w += (size_t)(NN+4)*4;
  int* col_ptr = (int*)w;   w += (size_t)(NN+4)*4;
  int* csr_col = (int*)w;   w += (size_t)NM*4;
  float* csr_val = (float*)w; w += (size_t)NM*4;
  int* csc_row = (int*)w;   w += (size_t)NM*4;
  float* csc_val = (float*)w; w += (size_t)NM*4;
  if ((size_t)(w - (char*)d_ws) > ws_size) return;  // insufficient scratch

  // zero bR, bC, maxu, denom (contiguous region at start of ws)
  int zero_u32s = (int)(((size_t)NN*W64*8*2 + (size_t)NN*HD*4 + (size_t)NN*4) / 4);
  hipLaunchKernelGGL(zero_kernel, dim3(2048), dim3(256), 0, stream, (u32*)d_ws, zero_u32s);
  hipLaunchKernelGGL(knn_kernel, dim3(NN/256), dim3(256), 0, stream, pts, knn_idx);
  hipLaunchKernelGGL(bitmap_kernel, dim3((NM+255)/256), dim3(256), 0, stream,
                     ei, knn_idx, bR, bC);
  hipLaunchKernelGGL(theta_max_kernel, dim3((NM*HD+255)/256), dim3(256), 0, stream,
                     pts, ei, knn_idx, Wt, bt, maxu);
  hipLaunchKernelGGL(dev_qk_kernel, dim3(NN/4), dim3(256), 0, stream,
                     maxu, Wp, bp, Wq, bq, Wk, bk, qv, kv);
  hipLaunchKernelGGL(denom_kernel, dim3((NM+255)/256), dim3(256), 0, stream,
                     ei, knn_idx, qv, kv, denom);
  hipLaunchKernelGGL(deg_kernel, dim3(NN/256), dim3(256), 0, stream, bR, bC, outdeg, indeg);
  hipLaunchKernelGGL(scan_kernel, dim3(1), dim3(1024), 0, stream, outdeg, row_ptr);
  hipLaunchKernelGGL(scan_kernel, dim3(1), dim3(1024), 0, stream, indeg, col_ptr);
  hipLaunchKernelGGL(fill_csr_kernel, dim3(NN/256), dim3(256), 0, stream,
                     bR, row_ptr, qv, kv, denom, csr_col, csr_val);
  hipLaunchKernelGGL(fill_csc_kernel, dim3(NN/256), dim3(256), 0, stream,
                     bC, col_ptr, qv, kv, denom, csc_row, csc_val);
  hipLaunchKernelGGL(final_kernel, dim3(NN), dim3(256), 0, stream,
                     row_ptr, csr_col, csr_val, col_ptr, csc_row, csc_val, out);
}

// Round 2
// 784.106 us; speedup vs baseline: 6.3472x; 6.3472x over previous
//
#include <hip/hip_runtime.h>

#define NN 4096
#define HD 64
#define KNB 15
#define NE 32768
#define NM (NE + NN*KNB)   // 94208 edges total (with duplicates)
#define W64 (NN/64)        // 64 u64 words per bitmap row

typedef unsigned long long u64;
typedef unsigned int u32;

__device__ __forceinline__ float wave_sum(float v) {
#pragma unroll
  for (int off = 32; off >= 1; off >>= 1) v += __shfl_xor(v, off, 64);
  return v;
}

__device__ __forceinline__ void edge_decode(int m, const int* __restrict__ ei,
                                            const int* __restrict__ knn_idx,
                                            int& s, int& d) {
  if (m < NE) { s = ei[m]; d = ei[NE + m]; }
  else { int mm = m - NE; s = mm / KNB; d = knn_idx[mm]; }
}

__global__ void zero_kernel(u32* __restrict__ p, int n) {
  int i = blockIdx.x * 256 + threadIdx.x;
  int stride = gridDim.x * 256;
  for (; i < n; i += stride) p[i] = 0u;
}

// ---------- KNN: wave per node; lane-private top-15 + wave merge ----------
__global__ __launch_bounds__(512) void knn_kernel(const float* __restrict__ pts,
                                                  int* __restrict__ knn_idx) {
  __shared__ float4 sp[NN];  // x,y,z,|p|^2 : 64KB
  int tid = threadIdx.x;
  for (int j = tid; j < NN; j += 512) {
    float x = pts[j*3+0], y = pts[j*3+1], z = pts[j*3+2];
    // match np: (x*x + y*y) + z*z, no fma contraction
    float sq = __fadd_rn(__fadd_rn(__fmul_rn(x,x), __fmul_rn(y,y)), __fmul_rn(z,z));
    sp[j] = make_float4(x, y, z, sq);
  }
  __syncthreads();
  int lane = tid & 63, wv = tid >> 6;
  int i = blockIdx.x * 8 + wv;
  float4 pi = sp[i];
  float bd[KNB]; int bi[KNB];
#pragma unroll
  for (int s = 0; s < KNB; ++s) { bd[s] = INFINITY; bi[s] = NN + 1; }
  // lane scans j = t*64 + lane : disjoint index sets across lanes
  for (int t = 0; t < NN/64; ++t) {
    int j = t*64 + lane;
    float4 pj = sp[j];
    // match BLAS fma chain: acc = x*xj; fma(y,..); fma(z,..)
    float dot = fmaf(pi.z, pj.z, fmaf(pi.y, pj.y, __fmul_rn(pi.x, pj.x)));
    float d2 = __fadd_rn(__fsub_rn(pi.w, __fmul_rn(2.0f, dot)), pj.w);
    bool ins = (j != i) && (d2 < bd[KNB-1] ||
                            (d2 == bd[KNB-1] && j < bi[KNB-1]));
    if (ins) {
      bd[KNB-1] = d2; bi[KNB-1] = j;
#pragma unroll
      for (int s = KNB-1; s > 0; --s) {
        bool sw = (bd[s] < bd[s-1]) || (bd[s] == bd[s-1] && bi[s] < bi[s-1]);
        if (sw) {
          float td = bd[s]; bd[s] = bd[s-1]; bd[s-1] = td;
          int ti = bi[s]; bi[s] = bi[s-1]; bi[s-1] = ti;
        }
      }
    }
  }
  // wave merge: 15 rounds of lexicographic argmin over lane heads
#pragma unroll
  for (int s = 0; s < KNB; ++s) {
    float v = bd[0]; int id = bi[0];
#pragma unroll
    for (int off = 32; off >= 1; off >>= 1) {
      float ov = __shfl_xor(v, off, 64);
      int oi = __shfl_xor(id, off, 64);
      if (ov < v || (ov == v && oi < id)) { v = ov; id = oi; }
    }
    if (lane == 0) knn_idx[i*KNB + s] = id;
    if (bd[0] == v && bi[0] == id) {   // exactly one lane matches (ids unique)
#pragma unroll
      for (int r = 0; r < KNB-1; ++r) { bd[r] = bd[r+1]; bi[r] = bi[r+1]; }
      bd[KNB-1] = INFINITY; bi[KNB-1] = NN + 1;
    }
  }
}

// ---------- mark unique edges in row- and col-bitmaps ----------
__global__ void bitmap_kernel(const int* __restrict__ ei, const int* __restrict__ knn_idx,
                              u64* __restrict__ bR, u64* __restrict__ bC) {
  int m = blockIdx.x * 256 + threadIdx.x;
  if (m >= NM) return;
  int s, d; edge_decode(m, ei, knn_idx, s, d);
  atomicOr(&bR[(size_t)s*W64 + (d >> 6)], 1ull << (d & 63));
  atomicOr(&bC[(size_t)d*W64 + (s >> 6)], 1ull << (s & 63));
}

// ---------- degrees from bitmaps ----------
__global__ void deg_kernel(const u64* __restrict__ bR, const u64* __restrict__ bC,
                           int* __restrict__ outdeg, int* __restrict__ indeg) {
  int i = blockIdx.x * 256 + threadIdx.x;
  if (i >= NN) return;
  int c = 0;
  for (int w = 0; w < W64; ++w) c += __popcll(bR[(size_t)i*W64 + w]);
  outdeg[i] = c;
  c = 0;
  for (int w = 0; w < W64; ++w) c += __popcll(bC[(size_t)i*W64 + w]);
  indeg[i] = c;
}

// ---------- exclusive scan of 4096 ints, single block ----------
__global__ __launch_bounds__(1024) void scan_kernel(const int* __restrict__ deg,
                                                    int* __restrict__ ptr) {
  __shared__ int part[1024];
  int t = threadIdx.x;
  int base = t * 4;
  int a0 = deg[base], a1 = deg[base+1], a2 = deg[base+2], a3 = deg[base+3];
  part[t] = a0 + a1 + a2 + a3;
  __syncthreads();
  for (int off = 1; off < 1024; off <<= 1) {
    int v = 0;
    if (t >= off) v = part[t - off];
    __syncthreads();
    if (t >= off) part[t] += v;
    __syncthreads();
  }
  int excl = (t > 0) ? part[t-1] : 0;
  ptr[base]   = excl;
  ptr[base+1] = excl + a0;
  ptr[base+2] = excl + a0 + a1;
  ptr[base+3] = excl + a0 + a1 + a2;
  if (t == 1023) ptr[NN] = part[1023];
}

// ---------- compressed index fill from bitmap (cols for CSR / rows for CSC) --
__global__ void fill_cols_kernel(const u64* __restrict__ bm, const int* __restrict__ ptr,
                                 int* __restrict__ idx_out) {
  int i = blockIdx.x * 256 + threadIdx.x;
  if (i >= NN) return;
  int off = ptr[i];
  for (int w = 0; w < W64; ++w) {
    u64 b = bm[(size_t)i*W64 + w];
    while (b) {
      int t = __builtin_ctzll(b); b &= b - 1;
      idx_out[off++] = w*64 + t;
    }
  }
}

// ---------- per-node max_j W_theta(p_j - p_i) over unique out-neighbors -----
// (max over duplicates == max over unique set, so CSR is valid here)
__global__ __launch_bounds__(256) void theta_max_kernel(const float* __restrict__ pts,
    const int* __restrict__ row_ptr, const int* __restrict__ csr_col,
    const float* __restrict__ Wt, const float* __restrict__ bt,
    float* __restrict__ maxf) {
  int lane = threadIdx.x & 63, wv = threadIdx.x >> 6;
  int i = blockIdx.x * 4 + wv;
  float w0 = Wt[lane*3+0], w1 = Wt[lane*3+1], w2 = Wt[lane*3+2], bb = bt[lane];
  float px = pts[i*3+0], py = pts[i*3+1], pz = pts[i*3+2];
  float m = -INFINITY;
  int rb = row_ptr[i], re = row_ptr[i+1];
  for (int e = rb; e < re; ++e) {
    int d = csr_col[e];
    float dx = __fsub_rn(pts[d*3+0], px);
    float dy = __fsub_rn(pts[d*3+1], py);
    float dz = __fsub_rn(pts[d*3+2], pz);
    float t = fmaf(dz, w2, fmaf(dy, w1, __fmul_rn(dx, w0)));
    m = fmaxf(m, __fadd_rn(t, bb));
  }
  maxf[(size_t)i*HD + lane] = m;
}

// ---------- dev = relu(W_phi maxf + b); q, k ----------
__global__ __launch_bounds__(256) void dev_qk_kernel(const float* __restrict__ maxf,
    const float* __restrict__ Wp, const float* __restrict__ bp,
    const float* __restrict__ Wq, const float* __restrict__ bq,
    const float* __restrict__ Wk, const float* __restrict__ bk,
    float* __restrict__ qv, float* __restrict__ kv) {
  __shared__ float mf[4][HD];
  __shared__ float dv[4][HD];
  int lane = threadIdx.x & 63, sub = threadIdx.x >> 6;
  int node = blockIdx.x * 4 + sub;
  mf[sub][lane] = maxf[(size_t)node*HD + lane];
  __syncthreads();
  float a = 0.f;
#pragma unroll
  for (int t = 0; t < HD; ++t) a = fmaf(Wp[lane*HD + t], mf[sub][t], a);
  float dvv = a + bp[lane];
  dv[sub][lane] = dvv > 0.f ? dvv : 0.f;
  __syncthreads();
  float aq = 0.f, ak = 0.f;
#pragma unroll
  for (int t = 0; t < HD; ++t) {
    float x = dv[sub][t];
    aq = fmaf(Wq[lane*HD + t], x, aq);
    ak = fmaf(Wk[lane*HD + t], x, ak);
  }
  qv[(size_t)node*HD + lane] = aq + bq[lane];
  kv[(size_t)node*HD + lane] = ak + bk[lane];
}

// ---------- denom[s] = sum over ALL M edges (incl. duplicates) ----------
__global__ void denom_kernel(const int* __restrict__ ei, const int* __restrict__ knn_idx,
                             const float* __restrict__ qv, const float* __restrict__ kv,
                             float* __restrict__ denom) {
  int g = blockIdx.x * 256 + threadIdx.x;
  int m = g >> 6, lane = g & 63;
  if (m >= NM) return;
  int s, d; edge_decode(m, ei, knn_idx, s, d);
  float prod = qv[(size_t)d*HD + lane] * kv[(size_t)s*HD + lane];
  float sum = wave_sum(prod);
  if (lane == 0) atomicAdd(&denom[s], expf(sum));
}

// ---------- attn values for CSR rows ----------
__global__ __launch_bounds__(256) void csr_vals_kernel(const int* __restrict__ row_ptr,
    const int* __restrict__ csr_col, const float* __restrict__ qv,
    const float* __restrict__ kv, const float* __restrict__ denom,
    float* __restrict__ csr_val) {
  int lane = threadIdx.x & 63, wv = threadIdx.x >> 6;
  int i = blockIdx.x * 4 + wv;
  float ki = kv[(size_t)i*HD + lane];
  float dn = denom[i];
  int rb = row_ptr[i], re = row_ptr[i+1];
  for (int e = rb; e < re; ++e) {
    int col = csr_col[e];
    float s = wave_sum(qv[(size_t)col*HD + lane] * ki);
    if (lane == 0) csr_val[e] = expf(s) / dn;
  }
}

// ---------- attn values for CSC cols ----------
__global__ __launch_bounds__(256) void csc_vals_kernel(const int* __restrict__ col_ptr,
    const int* __restrict__ csc_row, const float* __restrict__ qv,
    const float* __restrict__ kv, const float* __restrict__ denom,
    float* __restrict__ csc_val) {
  int lane = threadIdx.x & 63, wv = threadIdx.x >> 6;
  int l = blockIdx.x * 4 + wv;
  float ql = qv[(size_t)l*HD + lane];
  int cb = col_ptr[l], ce = col_ptr[l+1];
  for (int e = cb; e < ce; ++e) {
    int j = csc_row[e];
    float s = wave_sum(ql * kv[(size_t)j*HD + lane]);
    if (lane == 0) csc_val[e] = expf(s) / denom[j];
  }
}

// ---------- A_s row i = sum_l T[i,l] * attn[:,l], T = attn@A ----------
__global__ __launch_bounds__(256) void final_kernel(
    const int* __restrict__ row_ptr, const int* __restrict__ csr_col,
    const float* __restrict__ csr_val,
    const int* __restrict__ col_ptr, const int* __restrict__ csc_row,
    const float* __restrict__ csc_val,
    float* __restrict__ out) {
  __shared__ float Trow[NN];  // 16KB
  __shared__ float acc[NN];   // 16KB
  int tid = threadIdx.x;
  int i = blockIdx.x;
  for (int t = tid; t < NN; t += 256) { Trow[t] = 0.f; acc[t] = 0.f; }
  __syncthreads();
  int rb = row_ptr[i], re = row_ptr[i+1];
  int wave = tid >> 6, lane = tid & 63;
  // Phase A: Trow[l] += w_ik for l in out(k), k in out(i)
  for (int idx = rb + wave; idx < re; idx += 4) {
    int k = csr_col[idx]; float wv = csr_val[idx];
    int kb = row_ptr[k], ke = row_ptr[k+1];
    for (int t = kb + lane; t < ke; t += 64) {
      atomicAdd(&Trow[csr_col[t]], wv);
    }
  }
  __syncthreads();
  // Phase B: acc[j] += Trow[l] * attn[j,l]
  for (int l = tid; l < NN; l += 256) {
    float tv = Trow[l];
    if (tv != 0.f) {
      int cb = col_ptr[l], ce = col_ptr[l+1];
      for (int t = cb; t < ce; ++t) {
        atomicAdd(&acc[csc_row[t]], tv * csc_val[t]);
      }
    }
  }
  __syncthreads();
  float4* o = (float4*)(out + (size_t)i * NN);
  const float4* a4 = (const float4*)acc;
  for (int t = tid; t < NN/4; t += 256) o[t] = a4[t];
}

extern "C" void kernel_launch(void* const* d_in, const int* in_sizes, int n_in,
                              void* d_out, int out_size, void* d_ws, size_t ws_size,
                              hipStream_t stream) {
  (void)in_sizes; (void)n_in; (void)out_size;
  const float* pts = (const float*)d_in[0];
  // d_in[1] = features: unused by the reference
  const int* ei = (const int*)d_in[2];
  const float* Wt = (const float*)d_in[3];
  const float* bt = (const float*)d_in[4];
  const float* Wp = (const float*)d_in[5];
  const float* bp = (const float*)d_in[6];
  const float* Wq = (const float*)d_in[7];
  const float* bq = (const float*)d_in[8];
  const float* Wk = (const float*)d_in[9];
  const float* bk = (const float*)d_in[10];
  float* out = (float*)d_out;

  char* w = (char*)d_ws;
  // zeroed region first (contiguous): bR, bC, denom
  u64* bR = (u64*)w;        w += (size_t)NN*W64*8;   // 2MB
  u64* bC = (u64*)w;        w += (size_t)NN*W64*8;   // 2MB
  float* denom = (float*)w; w += (size_t)NN*4;       // 16KB
  float* maxf = (float*)w;  w += (size_t)NN*HD*4;    // 1MB
  float* qv = (float*)w;    w += (size_t)NN*HD*4;    // 1MB
  float* kv = (float*)w;    w += (size_t)NN*HD*4;    // 1MB
  int* knn_idx = (int*)w;   w += (size_t)NN*KNB*4;
  int* outdeg = (int*)w;    w += (size_t)NN*4;
  int* indeg = (int*)w;     w += (size_t)NN*4;
  int* row_ptr = (int*)w;   w += (size_t)(NN+4)*4;
  int* col_ptr = (int*)w;   w += (size_t)(NN+4)*4;
  int* csr_col = (int*)w;   w += (size_t)NM*4;
  float* csr_val = (float*)w; w += (size_t)NM*4;
  int* csc_row = (int*)w;   w += (size_t)NM*4;
  float* csc_val = (float*)w; w += (size_t)NM*4;
  if ((size_t)(w - (char*)d_ws) > ws_size) return;  // insufficient scratch

  int zero_u32s = (int)(((size_t)NN*W64*8*2 + (size_t)NN*4) / 4);
  hipLaunchKernelGGL(zero_kernel, dim3(2048), dim3(256), 0, stream, (u32*)d_ws, zero_u32s);
  hipLaunchKernelGGL(knn_kernel, dim3(NN/8), dim3(512), 0, stream, pts, knn_idx);
  hipLaunchKernelGGL(bitmap_kernel, dim3((NM+255)/256), dim3(256), 0, stream,
                     ei, knn_idx, bR, bC);
  hipLaunchKernelGGL(deg_kernel, dim3(NN/256), dim3(256), 0, stream, bR, bC, outdeg, indeg);
  hipLaunchKernelGGL(scan_kernel, dim3(1), dim3(1024), 0, stream, outdeg, row_ptr);
  hipLaunchKernelGGL(scan_kernel, dim3(1), dim3(1024), 0, stream, indeg, col_ptr);
  hipLaunchKernelGGL(fill_cols_kernel, dim3(NN/256), dim3(256), 0, stream,
                     bR, row_ptr, csr_col);
  hipLaunchKernelGGL(fill_cols_kernel, dim3(NN/256), dim3(256), 0, stream,
                     bC, col_ptr, csc_row);
  hipLaunchKernelGGL(theta_max_kernel, dim3(NN/4), dim3(256), 0, stream,
                     pts, row_ptr, csr_col, Wt, bt, maxf);
  hipLaunchKernelGGL(dev_qk_kernel, dim3(NN/4), dim3(256), 0, stream,
                     maxf, Wp, bp, Wq, bq, Wk, bk, qv, kv);
  hipLaunchKernelGGL(denom_kernel, dim3((NM*HD+255)/256), dim3(256), 0, stream,
                     ei, knn_idx, qv, kv, denom);
  hipLaunchKernelGGL(csr_vals_kernel, dim3(NN/4), dim3(256), 0, stream,
                     row_ptr, csr_col, qv, kv, denom, csr_val);
  hipLaunchKernelGGL(csc_vals_kernel, dim3(NN/4), dim3(256), 0, stream,
                     col_ptr, csc_row, qv, kv, denom, csc_val);
  hipLaunchKernelGGL(final_kernel, dim3(NN), dim3(256), 0, stream,
                     row_ptr, csr_col, csr_val, col_ptr, csc_row, csc_val, out);
}

// Round 3
// 462.290 us; speedup vs baseline: 10.7656x; 1.6961x over previous
//
#include <hip/hip_runtime.h>

#define NN 4096
#define HD 64
#define KNB 15
#define NE 32768
#define NM (NE + NN*KNB)   // 94208 edges total (with duplicates)
#define W64 (NN/64)        // 64 u64 words per bitmap row

typedef unsigned long long u64;
typedef unsigned int u32;

// order-preserving float->uint map
__device__ __forceinline__ u32 fmapu(float f) {
  int i = __float_as_int(f);
  return (u32)(i ^ ((i >> 31) | 0x80000000));
}

__device__ __forceinline__ float wave_sum(float v) {
#pragma unroll
  for (int off = 32; off >= 1; off >>= 1) v += __shfl_xor(v, off, 64);
  return v;
}

__device__ __forceinline__ void edge_decode(int m, const int* __restrict__ ei,
                                            const int* __restrict__ knn_idx,
                                            int& s, int& d) {
  if (m < NE) { s = ei[m]; d = ei[NE + m]; }
  else { int mm = m - NE; s = mm / KNB; d = knn_idx[mm]; }
}

__global__ void zero_kernel(u32* __restrict__ p, int n) {
  int i = blockIdx.x * 256 + threadIdx.x;
  int stride = gridDim.x * 256;
  for (; i < n; i += stride) p[i] = 0u;
}

// ---------- KNN: block per node; radix binary-search for 15th-smallest ------
// Order of the 15 neighbors is irrelevant downstream (set semantics), so we
// select the set {d2 < tau} plus smallest-index ties at tau, where tau is the
// 15th smallest key. Keys are order-preserving u32 maps of d2 (self -> MAX).
__global__ __launch_bounds__(256) void knn_kernel(const float* __restrict__ pts,
                                                  int* __restrict__ knn_idx) {
  __shared__ u32 s_wcnt[4];
  __shared__ int s_eq[256];
  __shared__ u32 s_cnt[2];   // [0]=strict-less slots, [1]=equal count
  int i = blockIdx.x;
  int tid = threadIdx.x;
  int lane = tid & 63, wv = tid >> 6;
  float px = pts[i*3+0], py = pts[i*3+1], pz = pts[i*3+2];
  // match np: (x*x + y*y) + z*z, no fma contraction
  float sqi = __fadd_rn(__fadd_rn(__fmul_rn(px,px), __fmul_rn(py,py)), __fmul_rn(pz,pz));
  u32 key[16];
#pragma unroll
  for (int s = 0; s < 16; ++s) {
    int j = s*256 + tid;
    float x = pts[j*3+0], y = pts[j*3+1], z = pts[j*3+2];
    float sqj = __fadd_rn(__fadd_rn(__fmul_rn(x,x), __fmul_rn(y,y)), __fmul_rn(z,z));
    // match BLAS fma chain: acc = x*xj; fma(y,..); fma(z,..)
    float dot = fmaf(pz, z, fmaf(py, y, __fmul_rn(px, x)));
    float d2 = __fadd_rn(__fsub_rn(sqi, __fmul_rn(2.0f, dot)), sqj);
    key[s] = (j == i) ? 0xFFFFFFFFu : fmapu(d2);
  }
  // binary search on bits: tau = 15th smallest key
  u32 prefix = 0u;
  for (int b = 31; b >= 0; --b) {
    u32 trial = prefix | (1u << b);
    u32 c = 0;
#pragma unroll
    for (int s = 0; s < 16; ++s) c += (key[s] < trial) ? 1u : 0u;
#pragma unroll
    for (int off = 32; off >= 1; off >>= 1) c += __shfl_xor((int)c, off, 64);
    if (lane == 0) s_wcnt[wv] = c;
    __syncthreads();
    u32 total = s_wcnt[0] + s_wcnt[1] + s_wcnt[2] + s_wcnt[3];
    if (total < KNB) prefix = trial;   // uniform across block
    __syncthreads();
  }
  u32 tau = prefix;
  if (tid == 0) { s_cnt[0] = 0u; s_cnt[1] = 0u; }
  __syncthreads();
#pragma unroll
  for (int s = 0; s < 16; ++s) {
    int j = s*256 + tid;
    if (key[s] < tau) {
      u32 p = atomicAdd(&s_cnt[0], 1u);
      knn_idx[i*KNB + p] = j;
    } else if (key[s] == tau) {
      u32 p = atomicAdd(&s_cnt[1], 1u);
      if (p < 256u) s_eq[p] = j;
    }
  }
  __syncthreads();
  if (tid == 0) {
    int cls = (int)s_cnt[0];
    int ceq = (int)s_cnt[1]; if (ceq > 256) ceq = 256;
    int need = KNB - cls;
    for (int r = 0; r < need; ++r) {      // smallest indices among ties
      int best = 1 << 30, bidx = 0;
      for (int t = 0; t < ceq; ++t) {
        int v = s_eq[t];
        if (v < best) { best = v; bidx = t; }
      }
      s_eq[bidx] = 1 << 30;
      knn_idx[i*KNB + cls + r] = best;
    }
  }
}

// ---------- mark unique edges in row- and col-bitmaps ----------
__global__ void bitmap_kernel(const int* __restrict__ ei, const int* __restrict__ knn_idx,
                              u64* __restrict__ bR, u64* __restrict__ bC) {
  int m = blockIdx.x * 256 + threadIdx.x;
  if (m >= NM) return;
  int s, d; edge_decode(m, ei, knn_idx, s, d);
  atomicOr(&bR[(size_t)s*W64 + (d >> 6)], 1ull << (d & 63));
  atomicOr(&bC[(size_t)d*W64 + (s >> 6)], 1ull << (s & 63));
}

// ---------- degrees from bitmaps ----------
__global__ void deg_kernel(const u64* __restrict__ bR, const u64* __restrict__ bC,
                           int* __restrict__ outdeg, int* __restrict__ indeg) {
  int i = blockIdx.x * 256 + threadIdx.x;
  if (i >= NN) return;
  int c = 0;
  for (int w = 0; w < W64; ++w) c += __popcll(bR[(size_t)i*W64 + w]);
  outdeg[i] = c;
  c = 0;
  for (int w = 0; w < W64; ++w) c += __popcll(bC[(size_t)i*W64 + w]);
  indeg[i] = c;
}

// ---------- exclusive scan of 4096 ints, single block ----------
__global__ __launch_bounds__(1024) void scan_kernel(const int* __restrict__ deg,
                                                    int* __restrict__ ptr) {
  __shared__ int part[1024];
  int t = threadIdx.x;
  int base = t * 4;
  int a0 = deg[base], a1 = deg[base+1], a2 = deg[base+2], a3 = deg[base+3];
  part[t] = a0 + a1 + a2 + a3;
  __syncthreads();
  for (int off = 1; off < 1024; off <<= 1) {
    int v = 0;
    if (t >= off) v = part[t - off];
    __syncthreads();
    if (t >= off) part[t] += v;
    __syncthreads();
  }
  int excl = (t > 0) ? part[t-1] : 0;
  ptr[base]   = excl;
  ptr[base+1] = excl + a0;
  ptr[base+2] = excl + a0 + a1;
  ptr[base+3] = excl + a0 + a1 + a2;
  if (t == 1023) ptr[NN] = part[1023];
}

// ---------- compressed index fill from bitmap ----------
__global__ void fill_cols_kernel(const u64* __restrict__ bm, const int* __restrict__ ptr,
                                 int* __restrict__ idx_out) {
  int i = blockIdx.x * 256 + threadIdx.x;
  if (i >= NN) return;
  int off = ptr[i];
  for (int w = 0; w < W64; ++w) {
    u64 b = bm[(size_t)i*W64 + w];
    while (b) {
      int t = __builtin_ctzll(b); b &= b - 1;
      idx_out[off++] = w*64 + t;
    }
  }
}

// ---------- per-node max_j W_theta(p_j - p_i) over unique out-neighbors -----
__global__ __launch_bounds__(256) void theta_max_kernel(const float* __restrict__ pts,
    const int* __restrict__ row_ptr, const int* __restrict__ csr_col,
    const float* __restrict__ Wt, const float* __restrict__ bt,
    float* __restrict__ maxf) {
  int lane = threadIdx.x & 63, wv = threadIdx.x >> 6;
  int i = blockIdx.x * 4 + wv;
  float w0 = Wt[lane*3+0], w1 = Wt[lane*3+1], w2 = Wt[lane*3+2], bb = bt[lane];
  float px = pts[i*3+0], py = pts[i*3+1], pz = pts[i*3+2];
  float m = -INFINITY;
  int rb = row_ptr[i], re = row_ptr[i+1];
  for (int e = rb; e < re; ++e) {
    int d = csr_col[e];
    float dx = __fsub_rn(pts[d*3+0], px);
    float dy = __fsub_rn(pts[d*3+1], py);
    float dz = __fsub_rn(pts[d*3+2], pz);
    float t = fmaf(dz, w2, fmaf(dy, w1, __fmul_rn(dx, w0)));
    m = fmaxf(m, __fadd_rn(t, bb));
  }
  maxf[(size_t)i*HD + lane] = m;
}

// ---------- dev = relu(W_phi maxf + b); q, k ----------
__global__ __launch_bounds__(256) void dev_qk_kernel(const float* __restrict__ maxf,
    const float* __restrict__ Wp, const float* __restrict__ bp,
    const float* __restrict__ Wq, const float* __restrict__ bq,
    const float* __restrict__ Wk, const float* __restrict__ bk,
    float* __restrict__ qv, float* __restrict__ kv) {
  __shared__ float mf[4][HD];
  __shared__ float dv[4][HD];
  int lane = threadIdx.x & 63, sub = threadIdx.x >> 6;
  int node = blockIdx.x * 4 + sub;
  mf[sub][lane] = maxf[(size_t)node*HD + lane];
  __syncthreads();
  float a = 0.f;
#pragma unroll
  for (int t = 0; t < HD; ++t) a = fmaf(Wp[lane*HD + t], mf[sub][t], a);
  float dvv = a + bp[lane];
  dv[sub][lane] = dvv > 0.f ? dvv : 0.f;
  __syncthreads();
  float aq = 0.f, ak = 0.f;
#pragma unroll
  for (int t = 0; t < HD; ++t) {
    float x = dv[sub][t];
    aq = fmaf(Wq[lane*HD + t], x, aq);
    ak = fmaf(Wk[lane*HD + t], x, ak);
  }
  qv[(size_t)node*HD + lane] = aq + bq[lane];
  kv[(size_t)node*HD + lane] = ak + bk[lane];
}

// ---------- denom[s] = sum over ALL M edges (incl. duplicates) ----------
__global__ void denom_kernel(const int* __restrict__ ei, const int* __restrict__ knn_idx,
                             const float* __restrict__ qv, const float* __restrict__ kv,
                             float* __restrict__ denom) {
  int g = blockIdx.x * 256 + threadIdx.x;
  int m = g >> 6, lane = g & 63;
  if (m >= NM) return;
  int s, d; edge_decode(m, ei, knn_idx, s, d);
  float prod = qv[(size_t)d*HD + lane] * kv[(size_t)s*HD + lane];
  float sum = wave_sum(prod);
  if (lane == 0) atomicAdd(&denom[s], expf(sum));
}

// ---------- attn values for CSR rows ----------
__global__ __launch_bounds__(256) void csr_vals_kernel(const int* __restrict__ row_ptr,
    const int* __restrict__ csr_col, const float* __restrict__ qv,
    const float* __restrict__ kv, const float* __restrict__ denom,
    float* __restrict__ csr_val) {
  int lane = threadIdx.x & 63, wv = threadIdx.x >> 6;
  int i = blockIdx.x * 4 + wv;
  float ki = kv[(size_t)i*HD + lane];
  float dn = denom[i];
  int rb = row_ptr[i], re = row_ptr[i+1];
  for (int e = rb; e < re; ++e) {
    int col = csr_col[e];
    float s = wave_sum(qv[(size_t)col*HD + lane] * ki);
    if (lane == 0) csr_val[e] = expf(s) / dn;
  }
}

// ---------- attn values for CSC cols ----------
__global__ __launch_bounds__(256) void csc_vals_kernel(const int* __restrict__ col_ptr,
    const int* __restrict__ csc_row, const float* __restrict__ qv,
    const float* __restrict__ kv, const float* __restrict__ denom,
    float* __restrict__ csc_val) {
  int lane = threadIdx.x & 63, wv = threadIdx.x >> 6;
  int l = blockIdx.x * 4 + wv;
  float ql = qv[(size_t)l*HD + lane];
  int cb = col_ptr[l], ce = col_ptr[l+1];
  for (int e = cb; e < ce; ++e) {
    int j = csc_row[e];
    float s = wave_sum(ql * kv[(size_t)j*HD + lane]);
    if (lane == 0) csc_val[e] = expf(s) / denom[j];
  }
}

// ---------- A_s row i = sum_l T[i,l] * attn[:,l], T = attn@A ----------
__global__ __launch_bounds__(256) void final_kernel(
    const int* __restrict__ row_ptr, const int* __restrict__ csr_col,
    const float* __restrict__ csr_val,
    const int* __restrict__ col_ptr, const int* __restrict__ csc_row,
    const float* __restrict__ csc_val,
    float* __restrict__ out) {
  __shared__ float Trow[NN];     // 16KB
  __shared__ float acc[NN];      // 16KB
  __shared__ u64 touched[64];    // bitmap of nonzero Trow entries
  int tid = threadIdx.x;
  int i = blockIdx.x;
  for (int t = tid; t < NN; t += 256) { Trow[t] = 0.f; acc[t] = 0.f; }
  if (tid < 64) touched[tid] = 0ull;
  __syncthreads();
  int rb = row_ptr[i], re = row_ptr[i+1];
  int wave = tid >> 6, lane = tid & 63;
  // Phase A: Trow[l] += w_ik for l in out(k), k in out(i); mark touched
  for (int idx = rb + wave; idx < re; idx += 4) {
    int k = csr_col[idx]; float wv = csr_val[idx];
    int kb = row_ptr[k], ke = row_ptr[k+1];
    for (int t = kb + lane; t < ke; t += 64) {
      int c = csr_col[t];
      atomicAdd(&Trow[c], wv);
      atomicOr(&touched[c >> 6], 1ull << (c & 63));
    }
  }
  __syncthreads();
  // Phase B: wave-cooperative scatter per touched column l
  for (int w = wave*16; w < wave*16 + 16; ++w) {
    u64 bits = touched[w];
    while (bits) {
      int t0 = __builtin_ctzll(bits); bits &= bits - 1;
      int l = w*64 + t0;
      float tv = Trow[l];
      int cb = col_ptr[l], ce = col_ptr[l+1];
      for (int t = cb + lane; t < ce; t += 64) {
        atomicAdd(&acc[csc_row[t]], tv * csc_val[t]);
      }
    }
  }
  __syncthreads();
  float4* o = (float4*)(out + (size_t)i * NN);
  const float4* a4 = (const float4*)acc;
  for (int t = tid; t < NN/4; t += 256) o[t] = a4[t];
}

extern "C" void kernel_launch(void* const* d_in, const int* in_sizes, int n_in,
                              void* d_out, int out_size, void* d_ws, size_t ws_size,
                              hipStream_t stream) {
  (void)in_sizes; (void)n_in; (void)out_size;
  const float* pts = (const float*)d_in[0];
  // d_in[1] = features: unused by the reference
  const int* ei = (const int*)d_in[2];
  const float* Wt = (const float*)d_in[3];
  const float* bt = (const float*)d_in[4];
  const float* Wp = (const float*)d_in[5];
  const float* bp = (const float*)d_in[6];
  const float* Wq = (const float*)d_in[7];
  const float* bq = (const float*)d_in[8];
  const float* Wk = (const float*)d_in[9];
  const float* bk = (const float*)d_in[10];
  float* out = (float*)d_out;

  char* w = (char*)d_ws;
  // zeroed region first (contiguous): bR, bC, denom
  u64* bR = (u64*)w;        w += (size_t)NN*W64*8;   // 2MB
  u64* bC = (u64*)w;        w += (size_t)NN*W64*8;   // 2MB
  float* denom = (float*)w; w += (size_t)NN*4;       // 16KB
  float* maxf = (float*)w;  w += (size_t)NN*HD*4;    // 1MB
  float* qv = (float*)w;    w += (size_t)NN*HD*4;    // 1MB
  float* kv = (float*)w;    w += (size_t)NN*HD*4;    // 1MB
  int* knn_idx = (int*)w;   w += (size_t)NN*KNB*4;
  int* outdeg = (int*)w;    w += (size_t)NN*4;
  int* indeg = (int*)w;     w += (size_t)NN*4;
  int* row_ptr = (int*)w;   w += (size_t)(NN+4)*4;
  int* col_ptr = (int*)w;   w += (size_t)(NN+4)*4;
  int* csr_col = (int*)w;   w += (size_t)NM*4;
  float* csr_val = (float*)w; w += (size_t)NM*4;
  int* csc_row = (int*)w;   w += (size_t)NM*4;
  float* csc_val = (float*)w; w += (size_t)NM*4;
  if ((size_t)(w - (char*)d_ws) > ws_size) return;  // insufficient scratch

  int zero_u32s = (int)(((size_t)NN*W64*8*2 + (size_t)NN*4) / 4);
  hipLaunchKernelGGL(zero_kernel, dim3(2048), dim3(256), 0, stream, (u32*)d_ws, zero_u32s);
  hipLaunchKernelGGL(knn_kernel, dim3(NN), dim3(256), 0, stream, pts, knn_idx);
  hipLaunchKernelGGL(bitmap_kernel, dim3((NM+255)/256), dim3(256), 0, stream,
                     ei, knn_idx, bR, bC);
  hipLaunchKernelGGL(deg_kernel, dim3(NN/256), dim3(256), 0, stream, bR, bC, outdeg, indeg);
  hipLaunchKernelGGL(scan_kernel, dim3(1), dim3(1024), 0, stream, outdeg, row_ptr);
  hipLaunchKernelGGL(scan_kernel, dim3(1), dim3(1024), 0, stream, indeg, col_ptr);
  hipLaunchKernelGGL(fill_cols_kernel, dim3(NN/256), dim3(256), 0, stream,
                     bR, row_ptr, csr_col);
  hipLaunchKernelGGL(fill_cols_kernel, dim3(NN/256), dim3(256), 0, stream,
                     bC, col_ptr, csc_row);
  hipLaunchKernelGGL(theta_max_kernel, dim3(NN/4), dim3(256), 0, stream,
                     pts, row_ptr, csr_col, Wt, bt, maxf);
  hipLaunchKernelGGL(dev_qk_kernel, dim3(NN/4), dim3(256), 0, stream,
                     maxf, Wp, bp, Wq, bq, Wk, bk, qv, kv);
  hipLaunchKernelGGL(denom_kernel, dim3((NM*HD+255)/256), dim3(256), 0, stream,
                     ei, knn_idx, qv, kv, denom);
  hipLaunchKernelGGL(csr_vals_kernel, dim3(NN/4), dim3(256), 0, stream,
                     row_ptr, csr_col, qv, kv, denom, csr_val);
  hipLaunchKernelGGL(csc_vals_kernel, dim3(NN/4), dim3(256), 0, stream,
                     col_ptr, csc_row, qv, kv, denom, csc_val);
  hipLaunchKernelGGL(final_kernel, dim3(NN), dim3(256), 0, stream,
                     row_ptr, csr_col, csr_val, col_ptr, csc_row, csc_val, out);
}

// Round 4
// 388.475 us; speedup vs baseline: 12.8112x; 1.1900x over previous
//
#include <hip/hip_runtime.h>

#define NN 4096
#define HD 64
#define KNB 15
#define NE 32768
#define NM (NE + NN*KNB)   // 94208 edges total (with duplicates)
#define W64 (NN/64)        // 64 u64 words per bitmap row

typedef unsigned long long u64;
typedef unsigned int u32;

// order-preserving float->uint map
__device__ __forceinline__ u32 fmapu(float f) {
  int i = __float_as_int(f);
  return (u32)(i ^ ((i >> 31) | 0x80000000));
}

__device__ __forceinline__ float dot64(const float* __restrict__ a,
                                       const float* __restrict__ b) {
  const float4* a4 = (const float4*)a;
  const float4* b4 = (const float4*)b;
  float s = 0.f;
#pragma unroll
  for (int t = 0; t < 16; ++t) {
    float4 x = a4[t], y = b4[t];
    s = fmaf(x.x, y.x, s); s = fmaf(x.y, y.y, s);
    s = fmaf(x.z, y.z, s); s = fmaf(x.w, y.w, s);
  }
  return s;
}

__device__ __forceinline__ void edge_decode(int m, const int* __restrict__ ei,
                                            const int* __restrict__ knn_idx,
                                            int& s, int& d) {
  if (m < NE) { s = ei[m]; d = ei[NE + m]; }
  else { int mm = m - NE; s = mm / KNB; d = knn_idx[mm]; }
}

__global__ void zero_kernel(u32* __restrict__ p, int n) {
  int i = blockIdx.x * 256 + threadIdx.x;
  int stride = gridDim.x * 256;
  for (; i < n; i += stride) p[i] = 0u;
}

// ---------- KNN: block per node; radix binary-search for 15th-smallest ------
__global__ __launch_bounds__(256) void knn_kernel(const float* __restrict__ pts,
                                                  int* __restrict__ knn_idx) {
  __shared__ u32 s_wcnt[4];
  __shared__ int s_eq[256];
  __shared__ u32 s_cnt[2];   // [0]=strict-less slots, [1]=equal count
  int i = blockIdx.x;
  int tid = threadIdx.x;
  int lane = tid & 63, wv = tid >> 6;
  float px = pts[i*3+0], py = pts[i*3+1], pz = pts[i*3+2];
  // match np: (x*x + y*y) + z*z, no fma contraction
  float sqi = __fadd_rn(__fadd_rn(__fmul_rn(px,px), __fmul_rn(py,py)), __fmul_rn(pz,pz));
  u32 key[16];
#pragma unroll
  for (int s = 0; s < 16; ++s) {
    int j = s*256 + tid;
    float x = pts[j*3+0], y = pts[j*3+1], z = pts[j*3+2];
    float sqj = __fadd_rn(__fadd_rn(__fmul_rn(x,x), __fmul_rn(y,y)), __fmul_rn(z,z));
    // match BLAS fma chain: acc = x*xj; fma(y,..); fma(z,..)
    float dot = fmaf(pz, z, fmaf(py, y, __fmul_rn(px, x)));
    float d2 = __fadd_rn(__fsub_rn(sqi, __fmul_rn(2.0f, dot)), sqj);
    key[s] = (j == i) ? 0xFFFFFFFFu : fmapu(d2);
  }
  // binary search on bits: tau = 15th smallest key
  u32 prefix = 0u;
  for (int b = 31; b >= 0; --b) {
    u32 trial = prefix | (1u << b);
    u32 c = 0;
#pragma unroll
    for (int s = 0; s < 16; ++s) c += (key[s] < trial) ? 1u : 0u;
#pragma unroll
    for (int off = 32; off >= 1; off >>= 1) c += __shfl_xor((int)c, off, 64);
    if (lane == 0) s_wcnt[wv] = c;
    __syncthreads();
    u32 total = s_wcnt[0] + s_wcnt[1] + s_wcnt[2] + s_wcnt[3];
    if (total < KNB) prefix = trial;   // uniform across block
    __syncthreads();
  }
  u32 tau = prefix;
  if (tid == 0) { s_cnt[0] = 0u; s_cnt[1] = 0u; }
  __syncthreads();
#pragma unroll
  for (int s = 0; s < 16; ++s) {
    int j = s*256 + tid;
    if (key[s] < tau) {
      u32 p = atomicAdd(&s_cnt[0], 1u);
      knn_idx[i*KNB + p] = j;
    } else if (key[s] == tau) {
      u32 p = atomicAdd(&s_cnt[1], 1u);
      if (p < 256u) s_eq[p] = j;
    }
  }
  __syncthreads();
  if (tid == 0) {
    int cls = (int)s_cnt[0];
    int ceq = (int)s_cnt[1]; if (ceq > 256) ceq = 256;
    int need = KNB - cls;
    for (int r = 0; r < need; ++r) {      // smallest indices among ties
      int best = 1 << 30, bidx = 0;
      for (int t = 0; t < ceq; ++t) {
        int v = s_eq[t];
        if (v < best) { best = v; bidx = t; }
      }
      s_eq[bidx] = 1 << 30;
      knn_idx[i*KNB + cls + r] = best;
    }
  }
}

// ---------- mark unique edges in row- and col-bitmaps ----------
__global__ void bitmap_kernel(const int* __restrict__ ei, const int* __restrict__ knn_idx,
                              u64* __restrict__ bR, u64* __restrict__ bC) {
  int m = blockIdx.x * 256 + threadIdx.x;
  if (m >= NM) return;
  int s, d; edge_decode(m, ei, knn_idx, s, d);
  atomicOr(&bR[(size_t)s*W64 + (d >> 6)], 1ull << (d & 63));
  atomicOr(&bC[(size_t)d*W64 + (s >> 6)], 1ull << (s & 63));
}

// ---------- degrees from bitmaps ----------
__global__ void deg_kernel(const u64* __restrict__ bR, const u64* __restrict__ bC,
                           int* __restrict__ outdeg, int* __restrict__ indeg) {
  int i = blockIdx.x * 256 + threadIdx.x;
  if (i >= NN) return;
  int c = 0;
  for (int w = 0; w < W64; ++w) c += __popcll(bR[(size_t)i*W64 + w]);
  outdeg[i] = c;
  c = 0;
  for (int w = 0; w < W64; ++w) c += __popcll(bC[(size_t)i*W64 + w]);
  indeg[i] = c;
}

// ---------- exclusive scans of 4096 ints: block 0 = row, block 1 = col ------
__global__ __launch_bounds__(1024) void scan_kernel(
    const int* __restrict__ outdeg, int* __restrict__ row_ptr,
    const int* __restrict__ indeg, int* __restrict__ col_ptr) {
  const int* deg = blockIdx.x ? indeg : outdeg;
  int* ptr = blockIdx.x ? col_ptr : row_ptr;
  __shared__ int part[1024];
  int t = threadIdx.x;
  int base = t * 4;
  int a0 = deg[base], a1 = deg[base+1], a2 = deg[base+2], a3 = deg[base+3];
  part[t] = a0 + a1 + a2 + a3;
  __syncthreads();
  for (int off = 1; off < 1024; off <<= 1) {
    int v = 0;
    if (t >= off) v = part[t - off];
    __syncthreads();
    if (t >= off) part[t] += v;
    __syncthreads();
  }
  int excl = (t > 0) ? part[t-1] : 0;
  ptr[base]   = excl;
  ptr[base+1] = excl + a0;
  ptr[base+2] = excl + a0 + a1;
  ptr[base+3] = excl + a0 + a1 + a2;
  if (t == 1023) ptr[NN] = part[1023];
}

// ---------- compressed fill from bitmaps: cols + owner id ----------
__global__ void fill_kernel(const u64* __restrict__ bR, const int* __restrict__ row_ptr,
                            int* __restrict__ csr_col, int* __restrict__ csr_rowid,
                            const u64* __restrict__ bC, const int* __restrict__ col_ptr,
                            int* __restrict__ csc_row, int* __restrict__ csc_colid) {
  int g = blockIdx.x * 256 + threadIdx.x;
  int i = g & (NN - 1);
  const u64* bm; const int* ptr; int* idx; int* own;
  if (g < NN) { bm = bR; ptr = row_ptr; idx = csr_col; own = csr_rowid; }
  else        { bm = bC; ptr = col_ptr; idx = csc_row; own = csc_colid; }
  int off = ptr[i];
  for (int w = 0; w < W64; ++w) {
    u64 b = bm[(size_t)i*W64 + w];
    while (b) {
      int t = __builtin_ctzll(b); b &= b - 1;
      idx[off] = w*64 + t; own[off] = i; ++off;
    }
  }
}

// ---------- per-node max_j W_theta(p_j - p_i) over unique out-neighbors -----
__global__ __launch_bounds__(256) void theta_max_kernel(const float* __restrict__ pts,
    const int* __restrict__ row_ptr, const int* __restrict__ csr_col,
    const float* __restrict__ Wt, const float* __restrict__ bt,
    float* __restrict__ maxf) {
  int lane = threadIdx.x & 63, wv = threadIdx.x >> 6;
  int i = blockIdx.x * 4 + wv;
  float w0 = Wt[lane*3+0], w1 = Wt[lane*3+1], w2 = Wt[lane*3+2], bb = bt[lane];
  float px = pts[i*3+0], py = pts[i*3+1], pz = pts[i*3+2];
  float m = -INFINITY;
  int rb = row_ptr[i], re = row_ptr[i+1];
  for (int e = rb; e < re; ++e) {
    int d = csr_col[e];
    float dx = __fsub_rn(pts[d*3+0], px);
    float dy = __fsub_rn(pts[d*3+1], py);
    float dz = __fsub_rn(pts[d*3+2], pz);
    float t = fmaf(dz, w2, fmaf(dy, w1, __fmul_rn(dx, w0)));
    m = fmaxf(m, __fadd_rn(t, bb));
  }
  maxf[(size_t)i*HD + lane] = m;
}

// ---------- dev = relu(W_phi maxf + b); q, k ----------
__global__ __launch_bounds__(256) void dev_qk_kernel(const float* __restrict__ maxf,
    const float* __restrict__ Wp, const float* __restrict__ bp,
    const float* __restrict__ Wq, const float* __restrict__ bq,
    const float* __restrict__ Wk, const float* __restrict__ bk,
    float* __restrict__ qv, float* __restrict__ kv) {
  __shared__ float mf[4][HD];
  __shared__ float dv[4][HD];
  int lane = threadIdx.x & 63, sub = threadIdx.x >> 6;
  int node = blockIdx.x * 4 + sub;
  mf[sub][lane] = maxf[(size_t)node*HD + lane];
  __syncthreads();
  float a = 0.f;
#pragma unroll
  for (int t = 0; t < HD; ++t) a = fmaf(Wp[lane*HD + t], mf[sub][t], a);
  float dvv = a + bp[lane];
  dv[sub][lane] = dvv > 0.f ? dvv : 0.f;
  __syncthreads();
  float aq = 0.f, ak = 0.f;
#pragma unroll
  for (int t = 0; t < HD; ++t) {
    float x = dv[sub][t];
    aq = fmaf(Wq[lane*HD + t], x, aq);
    ak = fmaf(Wk[lane*HD + t], x, ak);
  }
  qv[(size_t)node*HD + lane] = aq + bq[lane];
  kv[(size_t)node*HD + lane] = ak + bk[lane];
}

// ---------- denom[s] = sum over ALL M edges (incl. duplicates) ----------
__global__ void denom_kernel(const int* __restrict__ ei, const int* __restrict__ knn_idx,
                             const float* __restrict__ qv, const float* __restrict__ kv,
                             float* __restrict__ denom) {
  int m = blockIdx.x * 256 + threadIdx.x;
  if (m >= NM) return;
  int s, d; edge_decode(m, ei, knn_idx, s, d);
  float e = expf(dot64(qv + (size_t)d*HD, kv + (size_t)s*HD));
  atomicAdd(&denom[s], e);
}

// ---------- attn values, edge-parallel: first half CSR, second half CSC -----
__global__ void vals_kernel(const int* __restrict__ row_ptr,
    const int* __restrict__ csr_col, const int* __restrict__ csr_rowid,
    float* __restrict__ csr_val,
    const int* __restrict__ col_ptr, const int* __restrict__ csc_row,
    const int* __restrict__ csc_colid, float* __restrict__ csc_val,
    const float* __restrict__ qv, const float* __restrict__ kv,
    const float* __restrict__ denom) {
  int half = gridDim.x >> 1;
  bool is_csr = (int)blockIdx.x < half;
  int e = (is_csr ? blockIdx.x : blockIdx.x - half) * 256 + threadIdx.x;
  if (is_csr) {
    if (e >= row_ptr[NN]) return;
    int i = csr_rowid[e], col = csr_col[e];
    float s = dot64(qv + (size_t)col*HD, kv + (size_t)i*HD);
    csr_val[e] = expf(s) / denom[i];
  } else {
    if (e >= col_ptr[NN]) return;
    int l = csc_colid[e], j = csc_row[e];
    float s = dot64(qv + (size_t)l*HD, kv + (size_t)j*HD);
    csc_val[e] = expf(s) / denom[j];
  }
}

// ---------- A_s row i = sum_l T[i,l] * attn[:,l], T = attn@A ----------
__global__ __launch_bounds__(512) void final_kernel(
    const int* __restrict__ row_ptr, const int* __restrict__ csr_col,
    const float* __restrict__ csr_val,
    const int* __restrict__ col_ptr, const int* __restrict__ csc_row,
    const float* __restrict__ csc_val,
    float* __restrict__ out) {
  __shared__ float Trow[NN];     // 16KB
  __shared__ float acc[NN];      // 16KB
  int tid = threadIdx.x;
  int i = blockIdx.x;
  for (int t = tid; t < NN; t += 512) { Trow[t] = 0.f; acc[t] = 0.f; }
  __syncthreads();
  int rb = row_ptr[i], re = row_ptr[i+1];
  int wave = tid >> 6, lane = tid & 63;
  // Phase A: Trow[l] += w_ik for l in out(k), k in out(i)
  for (int idx = rb + wave; idx < re; idx += 8) {
    int k = csr_col[idx]; float wv = csr_val[idx];
    int kb = row_ptr[k], ke = row_ptr[k+1];
    for (int t = kb + lane; t < ke; t += 64)
      atomicAdd(&Trow[csr_col[t]], wv);
  }
  __syncthreads();
  // Phase B: column-per-thread; independent loads pipeline across lanes.
  // Trow entries are sums of positive attn products -> exact 0 means untouched.
  for (int l = tid; l < NN; l += 512) {
    float tv = Trow[l];
    if (tv != 0.f) {
      int cb = col_ptr[l], ce = col_ptr[l+1];
      for (int t = cb; t < ce; ++t)
        atomicAdd(&acc[csc_row[t]], tv * csc_val[t]);
    }
  }
  __syncthreads();
  float4* o = (float4*)(out + (size_t)i * NN);
  const float4* a4 = (const float4*)acc;
  for (int t = tid; t < NN/4; t += 512) o[t] = a4[t];
}

extern "C" void kernel_launch(void* const* d_in, const int* in_sizes, int n_in,
                              void* d_out, int out_size, void* d_ws, size_t ws_size,
                              hipStream_t stream) {
  (void)in_sizes; (void)n_in; (void)out_size;
  const float* pts = (const float*)d_in[0];
  // d_in[1] = features: unused by the reference
  const int* ei = (const int*)d_in[2];
  const float* Wt = (const float*)d_in[3];
  const float* bt = (const float*)d_in[4];
  const float* Wp = (const float*)d_in[5];
  const float* bp = (const float*)d_in[6];
  const float* Wq = (const float*)d_in[7];
  const float* bq = (const float*)d_in[8];
  const float* Wk = (const float*)d_in[9];
  const float* bk = (const float*)d_in[10];
  float* out = (float*)d_out;

  char* w = (char*)d_ws;
  // zeroed region first (contiguous): bR, bC, denom
  u64* bR = (u64*)w;        w += (size_t)NN*W64*8;   // 2MB
  u64* bC = (u64*)w;        w += (size_t)NN*W64*8;   // 2MB
  float* denom = (float*)w; w += (size_t)NN*4;       // 16KB
  float* maxf = (float*)w;  w += (size_t)NN*HD*4;    // 1MB
  float* qv = (float*)w;    w += (size_t)NN*HD*4;    // 1MB
  float* kv = (float*)w;    w += (size_t)NN*HD*4;    // 1MB
  int* knn_idx = (int*)w;   w += (size_t)NN*KNB*4;
  int* outdeg = (int*)w;    w += (size_t)NN*4;
  int* indeg = (int*)w;     w += (size_t)NN*4;
  int* row_ptr = (int*)w;   w += (size_t)(NN+4)*4;
  int* col_ptr = (int*)w;   w += (size_t)(NN+4)*4;
  int* csr_col = (int*)w;   w += (size_t)NM*4;
  int* csr_rowid = (int*)w; w += (size_t)NM*4;
  float* csr_val = (float*)w; w += (size_t)NM*4;
  int* csc_row = (int*)w;   w += (size_t)NM*4;
  int* csc_colid = (int*)w; w += (size_t)NM*4;
  float* csc_val = (float*)w; w += (size_t)NM*4;
  if ((size_t)(w - (char*)d_ws) > ws_size) return;  // insufficient scratch

  int zero_u32s = (int)(((size_t)NN*W64*8*2 + (size_t)NN*4) / 4);
  hipLaunchKernelGGL(zero_kernel, dim3(2048), dim3(256), 0, stream, (u32*)d_ws, zero_u32s);
  hipLaunchKernelGGL(knn_kernel, dim3(NN), dim3(256), 0, stream, pts, knn_idx);
  hipLaunchKernelGGL(bitmap_kernel, dim3((NM+255)/256), dim3(256), 0, stream,
                     ei, knn_idx, bR, bC);
  hipLaunchKernelGGL(deg_kernel, dim3(NN/256), dim3(256), 0, stream, bR, bC, outdeg, indeg);
  hipLaunchKernelGGL(scan_kernel, dim3(2), dim3(1024), 0, stream,
                     outdeg, row_ptr, indeg, col_ptr);
  hipLaunchKernelGGL(fill_kernel, dim3(2*NN/256), dim3(256), 0, stream,
                     bR, row_ptr, csr_col, csr_rowid, bC, col_ptr, csc_row, csc_colid);
  hipLaunchKernelGGL(theta_max_kernel, dim3(NN/4), dim3(256), 0, stream,
                     pts, row_ptr, csr_col, Wt, bt, maxf);
  hipLaunchKernelGGL(dev_qk_kernel, dim3(NN/4), dim3(256), 0, stream,
                     maxf, Wp, bp, Wq, bq, Wk, bk, qv, kv);
  hipLaunchKernelGGL(denom_kernel, dim3((NM+255)/256), dim3(256), 0, stream,
                     ei, knn_idx, qv, kv, denom);
  int vhalf = (NM+255)/256;
  hipLaunchKernelGGL(vals_kernel, dim3(2*vhalf), dim3(256), 0, stream,
                     row_ptr, csr_col, csr_rowid, csr_val,
                     col_ptr, csc_row, csc_colid, csc_val, qv, kv, denom);
  hipLaunchKernelGGL(final_kernel, dim3(NN), dim3(512), 0, stream,
                     row_ptr, csr_col, csr_val, col_ptr, csc_row, csc_val, out);
}